// Round 10
// baseline (968.159 us; speedup 1.0000x reference)
//
#include <hip/hip_runtime.h>

#define NN 100000      // nodes
#define NE 1600000     // edges
#define NG 2048        // graphs
#define DH 128         // feature dim
#define SCAN_B 391     // ceil(NN/256)

__device__ __forceinline__ float selu_f(float x) {
    return x > 0.f ? 1.0507009873554805f * x : 1.7580993408473766f * expm1f(x);
}

// ---------------- CSR build ----------------
// 4 edges per thread: 4 independent atomic chains in flight per lane.
__global__ __launch_bounds__(256) void k_deg(const int* __restrict__ dst, int* __restrict__ deg) {
    int base = blockIdx.x * 1024 + threadIdx.x;
    #pragma unroll
    for (int u = 0; u < 4; ++u) {
        int e = base + u * 256;
        if (e < NE) atomicAdd(deg + dst[e], 1);
    }
}

__global__ __launch_bounds__(256) void k_dinv(const int* __restrict__ deg, float* __restrict__ dinv) {
    int i = blockIdx.x * 256 + threadIdx.x;
    if (i < NN) dinv[i] = rsqrtf((float)deg[i] + 1.0f);
}

// per-256-chunk local exclusive scan; psum[b] = chunk total
__global__ __launch_bounds__(256) void k_scan1(const int* __restrict__ deg,
                                               int* __restrict__ rp_local, int* __restrict__ psum) {
    __shared__ int tmp[256];
    int t = threadIdx.x;
    int i = blockIdx.x * 256 + t;
    int v = (i < NN) ? deg[i] : 0;
    tmp[t] = v; __syncthreads();
    #pragma unroll
    for (int o = 1; o < 256; o <<= 1) {
        int u = (t >= o) ? tmp[t - o] : 0; __syncthreads();
        tmp[t] += u; __syncthreads();
    }
    if (i < NN) rp_local[i] = tmp[t] - v;
    if (t == 255) psum[blockIdx.x] = tmp[t];
}

// scan the 391 partials (single block of 512)
__global__ __launch_bounds__(512) void k_scan2(int* __restrict__ psum, int* __restrict__ rowptr) {
    __shared__ int tmp[512];
    int t = threadIdx.x;
    int v = (t < SCAN_B) ? psum[t] : 0;
    tmp[t] = v; __syncthreads();
    #pragma unroll
    for (int o = 1; o < 512; o <<= 1) {
        int u = (t >= o) ? tmp[t - o] : 0; __syncthreads();
        tmp[t] += u; __syncthreads();
    }
    if (t < SCAN_B) psum[t] = tmp[t] - v;   // exclusive
    if (t == 0) rowptr[NN] = NE;
}

__global__ __launch_bounds__(256) void k_scan3(const int* __restrict__ rp_local, const int* __restrict__ psum,
                                               int* __restrict__ rowptr, int* __restrict__ wptr) {
    int i = blockIdx.x * 256 + threadIdx.x;
    if (i < NN) {
        int v = rp_local[i] + psum[blockIdx.x];
        rowptr[i] = v;
        wptr[i] = v;
    }
}

// 4 edges per thread: 4 independent {load, atomic-RMW, scatter-store} chains.
__global__ __launch_bounds__(256) void k_fill(const int* __restrict__ src, const int* __restrict__ dst,
                                              int* __restrict__ wptr, int* __restrict__ csr_src) {
    int base = blockIdx.x * 1024 + threadIdx.x;
    #pragma unroll
    for (int u = 0; u < 4; ++u) {
        int e = base + u * 256;
        if (e < NE) {
            int pos = atomicAdd(wptr + dst[e], 1);
            csr_src[pos] = src[e];
        }
    }
}

// ---------------- GEMM:  X = (affine(H) @ W) * dinv[row] ----------------
template<int AFFINE>
__global__ __launch_bounds__(256) void k_gemm(
    const float* __restrict__ H, const float* __restrict__ W,
    const float* __restrict__ sc, const float* __restrict__ sh,
    const float* __restrict__ dinv, float* __restrict__ X)
{
    __shared__ float hs[64][132];
    __shared__ float ws[32][128];
    const int tid = threadIdx.x;
    const int base = blockIdx.x * 64;
    const int ct = tid & 15, rt = tid >> 4;
    const int r0 = rt * 4;
    const int cA = ct * 4, cB = cA + 64;

    #pragma unroll
    for (int i = 0; i < 8; ++i) {
        int idx4 = tid + i * 256;
        int r = idx4 >> 5;
        int c = (idx4 & 31) * 4;
        int row = base + r;
        float4 v = make_float4(0.f, 0.f, 0.f, 0.f);
        if (row < NN) v = *(const float4*)(H + (size_t)row * DH + c);
        if (AFFINE) {
            v.x = v.x * sc[c + 0] + sh[c + 0];
            v.y = v.y * sc[c + 1] + sh[c + 1];
            v.z = v.z * sc[c + 2] + sh[c + 2];
            v.w = v.w * sc[c + 3] + sh[c + 3];
        }
        *(float4*)&hs[r][c] = v;
    }

    float acc[4][8];
    #pragma unroll
    for (int i = 0; i < 4; ++i)
        #pragma unroll
        for (int j = 0; j < 8; ++j) acc[i][j] = 0.f;

    for (int kk = 0; kk < DH; kk += 32) {
        __syncthreads();
        #pragma unroll
        for (int i = 0; i < 4; ++i) {
            int idx4 = tid + i * 256;
            int k = idx4 >> 5;
            int c = (idx4 & 31) * 4;
            *(float4*)&ws[k][c] = *(const float4*)(W + (size_t)(kk + k) * DH + c);
        }
        __syncthreads();
        #pragma unroll
        for (int k = 0; k < 32; ++k) {
            float4 w0 = *(const float4*)&ws[k][cA];
            float4 w1 = *(const float4*)&ws[k][cB];
            #pragma unroll
            for (int i = 0; i < 4; ++i) {
                float h = hs[r0 + i][kk + k];
                acc[i][0] += h * w0.x; acc[i][1] += h * w0.y;
                acc[i][2] += h * w0.z; acc[i][3] += h * w0.w;
                acc[i][4] += h * w1.x; acc[i][5] += h * w1.y;
                acc[i][6] += h * w1.z; acc[i][7] += h * w1.w;
            }
        }
    }

    #pragma unroll
    for (int i = 0; i < 4; ++i) {
        int row = base + r0 + i;
        if (row < NN) {
            float di = dinv[row];
            float4 o0 = make_float4(acc[i][0] * di, acc[i][1] * di, acc[i][2] * di, acc[i][3] * di);
            float4 o1 = make_float4(acc[i][4] * di, acc[i][5] * di, acc[i][6] * di, acc[i][7] * di);
            *(float4*)(X + (size_t)row * DH + cA) = o0;
            *(float4*)(X + (size_t)row * DH + cB) = o1;
        }
    }
}

// -------- fused gather-aggregate + self-loop + bias + SELU --------
// One wave per node.  Coalesced per-wave index load + shfl broadcast.
// Half-wave (32 lanes x float4) covers one 512B row -> one VMEM instr
// gathers 2 edges; main loop keeps 4 such loads (8 edges) in flight.
__global__ __launch_bounds__(256) void k_agg(
    const float* __restrict__ X, const int* __restrict__ rowptr,
    const int* __restrict__ csr_src, const float* __restrict__ dinv,
    const float* __restrict__ bias, float* __restrict__ Y)
{
    int node = blockIdx.x * 4 + (threadIdx.x >> 6);
    if (node >= NN) return;
    const int lane = threadIdx.x & 63;
    const int half = lane >> 5;        // which edge of the pair this lane serves
    const int qc = lane & 31;          // float4 index within row
    const float4* __restrict__ X4 = (const float4*)X;   // row stride 32

    float4 accA = make_float4(0.f, 0.f, 0.f, 0.f);
    float4 accB = make_float4(0.f, 0.f, 0.f, 0.f);
    const int jb = rowptr[node], je = rowptr[node + 1];
    const int cnt = je - jb;

    for (int base = 0; base < cnt; base += 64) {
        int m = cnt - base; if (m > 64) m = 64;
        int idx_l = (base + lane < cnt) ? csr_src[jb + base + lane] : 0;
        int t = 0;
        // full 8-edge batches: no predication, 4 independent gathers in flight
        for (; t + 8 <= m; t += 8) {
            int iA = __shfl(idx_l, t + half);
            int iB = __shfl(idx_l, t + 2 + half);
            int iC = __shfl(idx_l, t + 4 + half);
            int iD = __shfl(idx_l, t + 6 + half);
            float4 vA = X4[(size_t)iA * 32 + qc];
            float4 vB = X4[(size_t)iB * 32 + qc];
            float4 vC = X4[(size_t)iC * 32 + qc];
            float4 vD = X4[(size_t)iD * 32 + qc];
            accA.x += vA.x; accA.y += vA.y; accA.z += vA.z; accA.w += vA.w;
            accB.x += vB.x; accB.y += vB.y; accB.z += vB.z; accB.w += vB.w;
            accA.x += vC.x; accA.y += vC.y; accA.z += vC.z; accA.w += vC.w;
            accB.x += vD.x; accB.y += vD.y; accB.z += vD.z; accB.w += vD.w;
        }
        // predicated tail (up to 7 edges), 4-edge stride
        for (; t < m; t += 4) {
            int eA = t + half;
            int eB = t + 2 + half;
            int iA = __shfl(idx_l, eA);
            int iB = __shfl(idx_l, eB);
            float wA = (eA < m) ? 1.f : 0.f;
            float wB = (eB < m) ? 1.f : 0.f;
            float4 vA = X4[(size_t)iA * 32 + qc];
            float4 vB = X4[(size_t)iB * 32 + qc];
            accA.x += wA * vA.x; accA.y += wA * vA.y; accA.z += wA * vA.z; accA.w += wA * vA.w;
            accB.x += wB * vB.x; accB.y += wB * vB.y; accB.z += wB * vB.z; accB.w += wB * vB.w;
        }
    }

    float4 acc;
    acc.x = accA.x + accB.x; acc.y = accA.y + accB.y;
    acc.z = accA.z + accB.z; acc.w = accA.w + accB.w;

    // combine the two half-wave partial sums (same channels in lanes l and l^32)
    acc.x += __shfl_xor(acc.x, 32);
    acc.y += __shfl_xor(acc.y, 32);
    acc.z += __shfl_xor(acc.z, 32);
    acc.w += __shfl_xor(acc.w, 32);

    if (half == 0) {
        float4 self = X4[(size_t)node * 32 + qc];
        float di = dinv[node];
        float4 bv = ((const float4*)bias)[qc];
        float4 o;
        o.x = selu_f(di * (acc.x + self.x) + bv.x);
        o.y = selu_f(di * (acc.y + self.y) + bv.y);
        o.z = selu_f(di * (acc.z + self.z) + bv.z);
        o.w = selu_f(di * (acc.w + self.w) + bv.w);
        ((float4*)Y)[(size_t)node * 32 + qc] = o;
    }
}

// ---------------- BN stats over Y ----------------
__global__ __launch_bounds__(256) void k_stats(const float* __restrict__ Y,
                                               float* __restrict__ ssum, float* __restrict__ ssq)
{
    const int tid = threadIdx.x;
    float s = 0.f, s2 = 0.f;
    const int total = NN * DH;
    const int stride = gridDim.x * 256;
    for (int idx = blockIdx.x * 256 + tid; idx < total; idx += stride) {
        float y = Y[idx];
        s += y; s2 += y * y;
    }
    __shared__ float r1[256], r2[256];
    r1[tid] = s; r2[tid] = s2;
    __syncthreads();
    if (tid < 128) {
        unsafeAtomicAdd(ssum + tid, r1[tid] + r1[tid + 128]);
        unsafeAtomicAdd(ssq + tid, r2[tid] + r2[tid + 128]);
    }
}

__global__ void k_bnfin(const float* __restrict__ ssum, const float* __restrict__ ssq,
                        const float* __restrict__ gamma, const float* __restrict__ beta,
                        float* __restrict__ sc, float* __restrict__ sh)
{
    int c = threadIdx.x;
    float mean = ssum[c] * (1.f / NN);
    float var = ssq[c] * (1.f / NN) - mean * mean;
    float s = gamma[c] * rsqrtf(var + 1e-5f);
    sc[c] = s;
    sh[c] = beta[c] - mean * s;
}

// ---------------- pooling: batch is sorted -> per-graph segment sum ----------------
__global__ __launch_bounds__(128) void k_pool(const float* __restrict__ Y,
                                              const int* __restrict__ batch, float* __restrict__ hg)
{
    int g = blockIdx.x;
    __shared__ int bounds[2];
    if (threadIdx.x < 2) {
        int target = g + threadIdx.x;
        int lo = 0, hi = NN;
        while (lo < hi) { int mid = (lo + hi) >> 1; if (batch[mid] < target) lo = mid + 1; else hi = mid; }
        bounds[threadIdx.x] = lo;
    }
    __syncthreads();
    int s = bounds[0], e = bounds[1];
    int c = threadIdx.x;
    float acc = 0.f;
    for (int i = s; i < e; ++i) acc += Y[(size_t)i * DH + c];
    hg[(size_t)g * DH + c] = acc;
}

// ---------------- final MLP ----------------
__global__ __launch_bounds__(128) void k_mlp(
    const float* __restrict__ hg, const float* __restrict__ mol,
    const float* __restrict__ Wf1, const float* __restrict__ bf1,
    const float* __restrict__ Wf2, const float* __restrict__ bf2,
    float* __restrict__ out)
{
    int g = blockIdx.x, c = threadIdx.x;
    __shared__ float in_s[192];
    in_s[c] = hg[(size_t)g * DH + c];
    if (c < 64) in_s[128 + c] = mol[(size_t)g * 64 + c];
    __syncthreads();
    float acc = bf1[c];
    #pragma unroll 8
    for (int k = 0; k < 192; ++k) acc += in_s[k] * Wf1[k * DH + c];
    float h = selu_f(acc);
    float pv = h * Wf2[c];
    #pragma unroll
    for (int o = 32; o > 0; o >>= 1) pv += __shfl_down(pv, o);
    __shared__ float wsum[2];
    if ((c & 63) == 0) wsum[c >> 6] = pv;
    __syncthreads();
    if (c == 0) out[g] = wsum[0] + wsum[1] + bf2[0];
}

extern "C" void kernel_launch(void* const* d_in, const int* in_sizes, int n_in,
                              void* d_out, int out_size, void* d_ws, size_t ws_size,
                              hipStream_t stream)
{
    const float* x   = (const float*)d_in[0];
    const int* ei    = (const int*)d_in[1];
    const int* batch = (const int*)d_in[2];
    const float* mol = (const float*)d_in[3];
    const float* W1  = (const float*)d_in[4];  const float* b1  = (const float*)d_in[5];
    const float* g1  = (const float*)d_in[6];  const float* be1 = (const float*)d_in[7];
    const float* W2  = (const float*)d_in[8];  const float* b2  = (const float*)d_in[9];
    const float* g2  = (const float*)d_in[10]; const float* be2 = (const float*)d_in[11];
    const float* W3  = (const float*)d_in[12]; const float* b3  = (const float*)d_in[13];
    const float* Wf1 = (const float*)d_in[14]; const float* bf1 = (const float*)d_in[15];
    const float* Wf2 = (const float*)d_in[16]; const float* bf2 = (const float*)d_in[17];
    const int* srcv = ei;
    const int* dstv = ei + NE;
    float* out = (float*)d_out;

    char* p = (char*)d_ws;
    size_t off = 0;
    auto alloc = [&](size_t bytes) { void* q = p + off; off += (bytes + 255) & ~(size_t)255; return q; };
    float* buf0   = (float*)alloc((size_t)NN * DH * 4);
    float* buf1   = (float*)alloc((size_t)NN * DH * 4);
    int*   deg    = (int*)alloc((size_t)NN * 4);
    float* dinv   = (float*)alloc((size_t)NN * 4);
    int*   rowptr = (int*)alloc((size_t)(NN + 1) * 4);
    int*   wptr   = (int*)alloc((size_t)NN * 4);
    int*   rp_loc = (int*)alloc((size_t)NN * 4);
    int*   psum   = (int*)alloc((size_t)512 * 4);
    int*   csr    = (int*)alloc((size_t)NE * 4);
    float* ssum   = (float*)alloc(512);
    float* ssq    = (float*)alloc(512);
    float* scb    = (float*)alloc(512);
    float* shb    = (float*)alloc(512);
    float* hg     = (float*)alloc((size_t)NG * DH * 4);

    const int NB = (NN + 255) / 256;   // = SCAN_B
    const int EB4 = (NE + 1023) / 1024;
    const int GB = (NN + 63) / 64;
    const int AB = (NN + 3) / 4;

    // ---- CSR build (amortized over 3 aggregations) ----
    hipMemsetAsync(deg, 0, (size_t)NN * 4, stream);
    k_deg<<<EB4, 256, 0, stream>>>(dstv, deg);
    k_dinv<<<NB, 256, 0, stream>>>(deg, dinv);
    k_scan1<<<NB, 256, 0, stream>>>(deg, rp_loc, psum);
    k_scan2<<<1, 512, 0, stream>>>(psum, rowptr);
    k_scan3<<<NB, 256, 0, stream>>>(rp_loc, psum, rowptr, wptr);
    k_fill<<<EB4, 256, 0, stream>>>(srcv, dstv, wptr, csr);

    // ---- Layer 1 ----
    k_gemm<0><<<GB, 256, 0, stream>>>(x, W1, nullptr, nullptr, dinv, buf0);
    k_agg<<<AB, 256, 0, stream>>>(buf0, rowptr, csr, dinv, b1, buf1);
    hipMemsetAsync(ssum, 0, 512, stream);
    hipMemsetAsync(ssq, 0, 512, stream);
    k_stats<<<512, 256, 0, stream>>>(buf1, ssum, ssq);
    k_bnfin<<<1, 128, 0, stream>>>(ssum, ssq, g1, be1, scb, shb);

    // ---- Layer 2 ----
    k_gemm<1><<<GB, 256, 0, stream>>>(buf1, W2, scb, shb, dinv, buf0);
    k_agg<<<AB, 256, 0, stream>>>(buf0, rowptr, csr, dinv, b2, buf1);
    hipMemsetAsync(ssum, 0, 512, stream);
    hipMemsetAsync(ssq, 0, 512, stream);
    k_stats<<<512, 256, 0, stream>>>(buf1, ssum, ssq);
    k_bnfin<<<1, 128, 0, stream>>>(ssum, ssq, g2, be2, scb, shb);

    // ---- Layer 3 ----
    k_gemm<1><<<GB, 256, 0, stream>>>(buf1, W3, scb, shb, dinv, buf0);
    k_agg<<<AB, 256, 0, stream>>>(buf0, rowptr, csr, dinv, b3, buf1);
    k_pool<<<NG, 128, 0, stream>>>(buf1, batch, hg);

    k_mlp<<<NG, 128, 0, stream>>>(hg, mol, Wf1, bf1, Wf2, bf2, out);
}

// Round 11
// 813.929 us; speedup vs baseline: 1.1895x; 1.1895x over previous
//
#include <hip/hip_runtime.h>

#define NN 100000      // nodes
#define NE 1600000     // edges
#define NG 2048        // graphs
#define DH 128         // feature dim
#define SCAN_B 391     // ceil(NN/256)

__device__ __forceinline__ float selu_f(float x) {
    return x > 0.f ? 1.0507009873554805f * x : 1.7580993408473766f * expm1f(x);
}

// f32 -> bf16 round-to-nearest-even (bit trick), and back
__device__ __forceinline__ unsigned short f2bf(float f) {
    unsigned int u = __float_as_uint(f);
    return (unsigned short)((u + 0x7FFFu + ((u >> 16) & 1u)) >> 16);
}
__device__ __forceinline__ float bf2f(unsigned short s) {
    return __uint_as_float(((unsigned int)s) << 16);
}

// ---------------- CSR build ----------------
__global__ __launch_bounds__(256) void k_deg(const int* __restrict__ dst, int* __restrict__ deg) {
    int base = blockIdx.x * 1024 + threadIdx.x;
    #pragma unroll
    for (int u = 0; u < 4; ++u) {
        int e = base + u * 256;
        if (e < NE) atomicAdd(deg + dst[e], 1);
    }
}

__global__ __launch_bounds__(256) void k_dinv(const int* __restrict__ deg, float* __restrict__ dinv) {
    int i = blockIdx.x * 256 + threadIdx.x;
    if (i < NN) dinv[i] = rsqrtf((float)deg[i] + 1.0f);
}

// per-256-chunk local exclusive scan; psum[b] = chunk total
__global__ __launch_bounds__(256) void k_scan1(const int* __restrict__ deg,
                                               int* __restrict__ rp_local, int* __restrict__ psum) {
    __shared__ int tmp[256];
    int t = threadIdx.x;
    int i = blockIdx.x * 256 + t;
    int v = (i < NN) ? deg[i] : 0;
    tmp[t] = v; __syncthreads();
    #pragma unroll
    for (int o = 1; o < 256; o <<= 1) {
        int u = (t >= o) ? tmp[t - o] : 0; __syncthreads();
        tmp[t] += u; __syncthreads();
    }
    if (i < NN) rp_local[i] = tmp[t] - v;
    if (t == 255) psum[blockIdx.x] = tmp[t];
}

// scan the 391 partials (single block of 512)
__global__ __launch_bounds__(512) void k_scan2(int* __restrict__ psum, int* __restrict__ rowptr) {
    __shared__ int tmp[512];
    int t = threadIdx.x;
    int v = (t < SCAN_B) ? psum[t] : 0;
    tmp[t] = v; __syncthreads();
    #pragma unroll
    for (int o = 1; o < 512; o <<= 1) {
        int u = (t >= o) ? tmp[t - o] : 0; __syncthreads();
        tmp[t] += u; __syncthreads();
    }
    if (t < SCAN_B) psum[t] = tmp[t] - v;   // exclusive
    if (t == 0) rowptr[NN] = NE;
}

__global__ __launch_bounds__(256) void k_scan3(const int* __restrict__ rp_local, const int* __restrict__ psum,
                                               int* __restrict__ rowptr, int* __restrict__ wptr) {
    int i = blockIdx.x * 256 + threadIdx.x;
    if (i < NN) {
        int v = rp_local[i] + psum[blockIdx.x];
        rowptr[i] = v;
        wptr[i] = v;
    }
}

__global__ __launch_bounds__(256) void k_fill(const int* __restrict__ src, const int* __restrict__ dst,
                                              int* __restrict__ wptr, int* __restrict__ csr_src) {
    int base = blockIdx.x * 1024 + threadIdx.x;
    #pragma unroll
    for (int u = 0; u < 4; ++u) {
        int e = base + u * 256;
        if (e < NE) {
            int pos = atomicAdd(wptr + dst[e], 1);
            csr_src[pos] = src[e];
        }
    }
}

// ---------------- GEMM:  X(bf16) = (affine(H) @ W) * dinv[row] ----------------
template<int AFFINE>
__global__ __launch_bounds__(256) void k_gemm(
    const float* __restrict__ H, const float* __restrict__ W,
    const float* __restrict__ sc, const float* __restrict__ sh,
    const float* __restrict__ dinv, unsigned short* __restrict__ X)
{
    __shared__ float hs[64][132];
    __shared__ float ws[32][128];
    const int tid = threadIdx.x;
    const int base = blockIdx.x * 64;
    const int ct = tid & 15, rt = tid >> 4;
    const int r0 = rt * 4;
    const int cA = ct * 4, cB = cA + 64;

    #pragma unroll
    for (int i = 0; i < 8; ++i) {
        int idx4 = tid + i * 256;
        int r = idx4 >> 5;
        int c = (idx4 & 31) * 4;
        int row = base + r;
        float4 v = make_float4(0.f, 0.f, 0.f, 0.f);
        if (row < NN) v = *(const float4*)(H + (size_t)row * DH + c);
        if (AFFINE) {
            v.x = v.x * sc[c + 0] + sh[c + 0];
            v.y = v.y * sc[c + 1] + sh[c + 1];
            v.z = v.z * sc[c + 2] + sh[c + 2];
            v.w = v.w * sc[c + 3] + sh[c + 3];
        }
        *(float4*)&hs[r][c] = v;
    }

    float acc[4][8];
    #pragma unroll
    for (int i = 0; i < 4; ++i)
        #pragma unroll
        for (int j = 0; j < 8; ++j) acc[i][j] = 0.f;

    for (int kk = 0; kk < DH; kk += 32) {
        __syncthreads();
        #pragma unroll
        for (int i = 0; i < 4; ++i) {
            int idx4 = tid + i * 256;
            int k = idx4 >> 5;
            int c = (idx4 & 31) * 4;
            *(float4*)&ws[k][c] = *(const float4*)(W + (size_t)(kk + k) * DH + c);
        }
        __syncthreads();
        #pragma unroll
        for (int k = 0; k < 32; ++k) {
            float4 w0 = *(const float4*)&ws[k][cA];
            float4 w1 = *(const float4*)&ws[k][cB];
            #pragma unroll
            for (int i = 0; i < 4; ++i) {
                float h = hs[r0 + i][kk + k];
                acc[i][0] += h * w0.x; acc[i][1] += h * w0.y;
                acc[i][2] += h * w0.z; acc[i][3] += h * w0.w;
                acc[i][4] += h * w1.x; acc[i][5] += h * w1.y;
                acc[i][6] += h * w1.z; acc[i][7] += h * w1.w;
            }
        }
    }

    #pragma unroll
    for (int i = 0; i < 4; ++i) {
        int row = base + r0 + i;
        if (row < NN) {
            float di = dinv[row];
            ushort4 o0 = make_ushort4(f2bf(acc[i][0] * di), f2bf(acc[i][1] * di),
                                      f2bf(acc[i][2] * di), f2bf(acc[i][3] * di));
            ushort4 o1 = make_ushort4(f2bf(acc[i][4] * di), f2bf(acc[i][5] * di),
                                      f2bf(acc[i][6] * di), f2bf(acc[i][7] * di));
            *(ushort4*)(X + (size_t)row * DH + cA) = o0;
            *(ushort4*)(X + (size_t)row * DH + cB) = o1;
        }
    }
}

// -------- fused gather-aggregate + self-loop + bias + SELU --------
// X is bf16: row = 256B.  Half-wave (32 lanes x ushort4=8B) covers one row,
// so one 64-lane VMEM instr gathers TWO edges; 4 loads (8 edges) in flight.
// Channel mapping identical to f32 version: lane qc owns channels qc*4..qc*4+3.
__global__ __launch_bounds__(256) void k_agg(
    const unsigned short* __restrict__ X, const int* __restrict__ rowptr,
    const int* __restrict__ csr_src, const float* __restrict__ dinv,
    const float* __restrict__ bias, float* __restrict__ Y)
{
    int node = blockIdx.x * 4 + (threadIdx.x >> 6);
    if (node >= NN) return;
    const int lane = threadIdx.x & 63;
    const int half = lane >> 5;
    const int qc = lane & 31;
    const ushort4* __restrict__ X4 = (const ushort4*)X;   // row stride 32

    float4 accA = make_float4(0.f, 0.f, 0.f, 0.f);
    float4 accB = make_float4(0.f, 0.f, 0.f, 0.f);
    const int jb = rowptr[node], je = rowptr[node + 1];
    const int cnt = je - jb;

    for (int base = 0; base < cnt; base += 64) {
        int m = cnt - base; if (m > 64) m = 64;
        int idx_l = (base + lane < cnt) ? csr_src[jb + base + lane] : 0;
        int t = 0;
        // full 8-edge batches: no predication, 4 independent gathers in flight
        for (; t + 8 <= m; t += 8) {
            int iA = __shfl(idx_l, t + half);
            int iB = __shfl(idx_l, t + 2 + half);
            int iC = __shfl(idx_l, t + 4 + half);
            int iD = __shfl(idx_l, t + 6 + half);
            ushort4 vA = X4[(size_t)iA * 32 + qc];
            ushort4 vB = X4[(size_t)iB * 32 + qc];
            ushort4 vC = X4[(size_t)iC * 32 + qc];
            ushort4 vD = X4[(size_t)iD * 32 + qc];
            accA.x += bf2f(vA.x); accA.y += bf2f(vA.y); accA.z += bf2f(vA.z); accA.w += bf2f(vA.w);
            accB.x += bf2f(vB.x); accB.y += bf2f(vB.y); accB.z += bf2f(vB.z); accB.w += bf2f(vB.w);
            accA.x += bf2f(vC.x); accA.y += bf2f(vC.y); accA.z += bf2f(vC.z); accA.w += bf2f(vC.w);
            accB.x += bf2f(vD.x); accB.y += bf2f(vD.y); accB.z += bf2f(vD.z); accB.w += bf2f(vD.w);
        }
        // predicated tail (up to 7 edges), 4-edge stride
        for (; t < m; t += 4) {
            int eA = t + half;
            int eB = t + 2 + half;
            int iA = __shfl(idx_l, eA);
            int iB = __shfl(idx_l, eB);
            float wA = (eA < m) ? 1.f : 0.f;
            float wB = (eB < m) ? 1.f : 0.f;
            ushort4 vA = X4[(size_t)iA * 32 + qc];
            ushort4 vB = X4[(size_t)iB * 32 + qc];
            accA.x += wA * bf2f(vA.x); accA.y += wA * bf2f(vA.y);
            accA.z += wA * bf2f(vA.z); accA.w += wA * bf2f(vA.w);
            accB.x += wB * bf2f(vB.x); accB.y += wB * bf2f(vB.y);
            accB.z += wB * bf2f(vB.z); accB.w += wB * bf2f(vB.w);
        }
    }

    float4 acc;
    acc.x = accA.x + accB.x; acc.y = accA.y + accB.y;
    acc.z = accA.z + accB.z; acc.w = accA.w + accB.w;

    acc.x += __shfl_xor(acc.x, 32);
    acc.y += __shfl_xor(acc.y, 32);
    acc.z += __shfl_xor(acc.z, 32);
    acc.w += __shfl_xor(acc.w, 32);

    if (half == 0) {
        ushort4 sv = X4[(size_t)node * 32 + qc];
        float di = dinv[node];
        float4 bv = ((const float4*)bias)[qc];
        float4 o;
        o.x = selu_f(di * (acc.x + bf2f(sv.x)) + bv.x);
        o.y = selu_f(di * (acc.y + bf2f(sv.y)) + bv.y);
        o.z = selu_f(di * (acc.z + bf2f(sv.z)) + bv.z);
        o.w = selu_f(di * (acc.w + bf2f(sv.w)) + bv.w);
        ((float4*)Y)[(size_t)node * 32 + qc] = o;
    }
}

// ---------------- BN stats over Y (f32) ----------------
__global__ __launch_bounds__(256) void k_stats(const float* __restrict__ Y,
                                               float* __restrict__ ssum, float* __restrict__ ssq)
{
    const int tid = threadIdx.x;
    float s = 0.f, s2 = 0.f;
    const int total = NN * DH;
    const int stride = gridDim.x * 256;
    for (int idx = blockIdx.x * 256 + tid; idx < total; idx += stride) {
        float y = Y[idx];
        s += y; s2 += y * y;
    }
    __shared__ float r1[256], r2[256];
    r1[tid] = s; r2[tid] = s2;
    __syncthreads();
    if (tid < 128) {
        unsafeAtomicAdd(ssum + tid, r1[tid] + r1[tid + 128]);
        unsafeAtomicAdd(ssq + tid, r2[tid] + r2[tid + 128]);
    }
}

__global__ void k_bnfin(const float* __restrict__ ssum, const float* __restrict__ ssq,
                        const float* __restrict__ gamma, const float* __restrict__ beta,
                        float* __restrict__ sc, float* __restrict__ sh)
{
    int c = threadIdx.x;
    float mean = ssum[c] * (1.f / NN);
    float var = ssq[c] * (1.f / NN) - mean * mean;
    float s = gamma[c] * rsqrtf(var + 1e-5f);
    sc[c] = s;
    sh[c] = beta[c] - mean * s;
}

// ---------------- pooling: batch is sorted -> per-graph segment sum ----------------
__global__ __launch_bounds__(128) void k_pool(const float* __restrict__ Y,
                                              const int* __restrict__ batch, float* __restrict__ hg)
{
    int g = blockIdx.x;
    __shared__ int bounds[2];
    if (threadIdx.x < 2) {
        int target = g + threadIdx.x;
        int lo = 0, hi = NN;
        while (lo < hi) { int mid = (lo + hi) >> 1; if (batch[mid] < target) lo = mid + 1; else hi = mid; }
        bounds[threadIdx.x] = lo;
    }
    __syncthreads();
    int s = bounds[0], e = bounds[1];
    int c = threadIdx.x;
    float acc = 0.f;
    for (int i = s; i < e; ++i) acc += Y[(size_t)i * DH + c];
    hg[(size_t)g * DH + c] = acc;
}

// ---------------- final MLP ----------------
__global__ __launch_bounds__(128) void k_mlp(
    const float* __restrict__ hg, const float* __restrict__ mol,
    const float* __restrict__ Wf1, const float* __restrict__ bf1,
    const float* __restrict__ Wf2, const float* __restrict__ bf2,
    float* __restrict__ out)
{
    int g = blockIdx.x, c = threadIdx.x;
    __shared__ float in_s[192];
    in_s[c] = hg[(size_t)g * DH + c];
    if (c < 64) in_s[128 + c] = mol[(size_t)g * 64 + c];
    __syncthreads();
    float acc = bf1[c];
    #pragma unroll 8
    for (int k = 0; k < 192; ++k) acc += in_s[k] * Wf1[k * DH + c];
    float h = selu_f(acc);
    float pv = h * Wf2[c];
    #pragma unroll
    for (int o = 32; o > 0; o >>= 1) pv += __shfl_down(pv, o);
    __shared__ float wsum[2];
    if ((c & 63) == 0) wsum[c >> 6] = pv;
    __syncthreads();
    if (c == 0) out[g] = wsum[0] + wsum[1] + bf2[0];
}

extern "C" void kernel_launch(void* const* d_in, const int* in_sizes, int n_in,
                              void* d_out, int out_size, void* d_ws, size_t ws_size,
                              hipStream_t stream)
{
    const float* x   = (const float*)d_in[0];
    const int* ei    = (const int*)d_in[1];
    const int* batch = (const int*)d_in[2];
    const float* mol = (const float*)d_in[3];
    const float* W1  = (const float*)d_in[4];  const float* b1  = (const float*)d_in[5];
    const float* g1  = (const float*)d_in[6];  const float* be1 = (const float*)d_in[7];
    const float* W2  = (const float*)d_in[8];  const float* b2  = (const float*)d_in[9];
    const float* g2  = (const float*)d_in[10]; const float* be2 = (const float*)d_in[11];
    const float* W3  = (const float*)d_in[12]; const float* b3  = (const float*)d_in[13];
    const float* Wf1 = (const float*)d_in[14]; const float* bf1 = (const float*)d_in[15];
    const float* Wf2 = (const float*)d_in[16]; const float* bf2 = (const float*)d_in[17];
    const int* srcv = ei;
    const int* dstv = ei + NE;
    float* out = (float*)d_out;

    char* p = (char*)d_ws;
    size_t off = 0;
    auto alloc = [&](size_t bytes) { void* q = p + off; off += (bytes + 255) & ~(size_t)255; return q; };
    float*          bufY  = (float*)alloc((size_t)NN * DH * 4);          // f32 activations
    unsigned short* bufX  = (unsigned short*)alloc((size_t)NN * DH * 2); // bf16 gather buffer
    int*   deg    = (int*)alloc((size_t)NN * 4);
    float* dinv   = (float*)alloc((size_t)NN * 4);
    int*   rowptr = (int*)alloc((size_t)(NN + 1) * 4);
    int*   wptr   = (int*)alloc((size_t)NN * 4);
    int*   rp_loc = (int*)alloc((size_t)NN * 4);
    int*   psum   = (int*)alloc((size_t)512 * 4);
    int*   csr    = (int*)alloc((size_t)NE * 4);
    float* ssum   = (float*)alloc(512);
    float* ssq    = (float*)alloc(512);
    float* scb    = (float*)alloc(512);
    float* shb    = (float*)alloc(512);
    float* hg     = (float*)alloc((size_t)NG * DH * 4);

    const int NB = (NN + 255) / 256;   // = SCAN_B
    const int EB4 = (NE + 1023) / 1024;
    const int GB = (NN + 63) / 64;
    const int AB = (NN + 3) / 4;

    // ---- CSR build (amortized over 3 aggregations) ----
    hipMemsetAsync(deg, 0, (size_t)NN * 4, stream);
    k_deg<<<EB4, 256, 0, stream>>>(dstv, deg);
    k_dinv<<<NB, 256, 0, stream>>>(deg, dinv);
    k_scan1<<<NB, 256, 0, stream>>>(deg, rp_loc, psum);
    k_scan2<<<1, 512, 0, stream>>>(psum, rowptr);
    k_scan3<<<NB, 256, 0, stream>>>(rp_loc, psum, rowptr, wptr);
    k_fill<<<EB4, 256, 0, stream>>>(srcv, dstv, wptr, csr);

    // ---- Layer 1 ----
    k_gemm<0><<<GB, 256, 0, stream>>>(x, W1, nullptr, nullptr, dinv, bufX);
    k_agg<<<AB, 256, 0, stream>>>(bufX, rowptr, csr, dinv, b1, bufY);
    hipMemsetAsync(ssum, 0, 512, stream);
    hipMemsetAsync(ssq, 0, 512, stream);
    k_stats<<<512, 256, 0, stream>>>(bufY, ssum, ssq);
    k_bnfin<<<1, 128, 0, stream>>>(ssum, ssq, g1, be1, scb, shb);

    // ---- Layer 2 ----
    k_gemm<1><<<GB, 256, 0, stream>>>(bufY, W2, scb, shb, dinv, bufX);
    k_agg<<<AB, 256, 0, stream>>>(bufX, rowptr, csr, dinv, b2, bufY);
    hipMemsetAsync(ssum, 0, 512, stream);
    hipMemsetAsync(ssq, 0, 512, stream);
    k_stats<<<512, 256, 0, stream>>>(bufY, ssum, ssq);
    k_bnfin<<<1, 128, 0, stream>>>(ssum, ssq, g2, be2, scb, shb);

    // ---- Layer 3 ----
    k_gemm<1><<<GB, 256, 0, stream>>>(bufY, W3, scb, shb, dinv, bufX);
    k_agg<<<AB, 256, 0, stream>>>(bufX, rowptr, csr, dinv, b3, bufY);
    k_pool<<<NG, 128, 0, stream>>>(bufY, batch, hg);

    k_mlp<<<NG, 128, 0, stream>>>(hg, mol, Wf1, bf1, Wf2, bf2, out);
}

// Round 12
// 762.025 us; speedup vs baseline: 1.2705x; 1.0681x over previous
//
#include <hip/hip_runtime.h>

#define NN 100000      // nodes
#define NE 1600000     // edges
#define NG 2048        // graphs
#define DH 128         // feature dim
#define SCAN_B 391     // ceil(NN/256)
#define NXCD 8
#define RNG 12500      // NN / NXCD

__device__ __forceinline__ float selu_f(float x) {
    return x > 0.f ? 1.0507009873554805f * x : 1.7580993408473766f * expm1f(x);
}

// f32 -> bf16 round-to-nearest-even (bit trick), and back
__device__ __forceinline__ unsigned short f2bf(float f) {
    unsigned int u = __float_as_uint(f);
    return (unsigned short)((u + 0x7FFFu + ((u >> 16) & 1u)) >> 16);
}
__device__ __forceinline__ float bf2f(unsigned short s) {
    return __uint_as_float(((unsigned int)s) << 16);
}

// ---------------- CSR build ----------------
// XCD-partitioned scatter: blocks with blockIdx%8==x handle only dst in
// [x*RNG,(x+1)*RNG).  Under round-robin block->XCD dispatch, each 800KB csr
// slice (and 50KB deg slice) is touched by ONE XCD's L2 -> lines fill fully
// before writeback.  Correct under ANY dispatch mapping (perf-only heuristic).
__global__ __launch_bounds__(256) void k_deg(const int* __restrict__ dst, int* __restrict__ deg) {
    const int grp = blockIdx.x & (NXCD - 1);
    const int slice = blockIdx.x >> 3;
    const int B = gridDim.x >> 3;
    const int lo = grp * RNG, hi = lo + RNG;
    for (int e = slice * 256 + threadIdx.x; e < NE; e += B * 256) {
        int d = dst[e];
        if (d >= lo && d < hi) atomicAdd(deg + d, 1);
    }
}

__global__ __launch_bounds__(256) void k_dinv(const int* __restrict__ deg, float* __restrict__ dinv) {
    int i = blockIdx.x * 256 + threadIdx.x;
    if (i < NN) dinv[i] = rsqrtf((float)deg[i] + 1.0f);
}

// per-256-chunk local exclusive scan; psum[b] = chunk total
__global__ __launch_bounds__(256) void k_scan1(const int* __restrict__ deg,
                                               int* __restrict__ rp_local, int* __restrict__ psum) {
    __shared__ int tmp[256];
    int t = threadIdx.x;
    int i = blockIdx.x * 256 + t;
    int v = (i < NN) ? deg[i] : 0;
    tmp[t] = v; __syncthreads();
    #pragma unroll
    for (int o = 1; o < 256; o <<= 1) {
        int u = (t >= o) ? tmp[t - o] : 0; __syncthreads();
        tmp[t] += u; __syncthreads();
    }
    if (i < NN) rp_local[i] = tmp[t] - v;
    if (t == 255) psum[blockIdx.x] = tmp[t];
}

// scan the 391 partials (single block of 512)
__global__ __launch_bounds__(512) void k_scan2(int* __restrict__ psum, int* __restrict__ rowptr) {
    __shared__ int tmp[512];
    int t = threadIdx.x;
    int v = (t < SCAN_B) ? psum[t] : 0;
    tmp[t] = v; __syncthreads();
    #pragma unroll
    for (int o = 1; o < 512; o <<= 1) {
        int u = (t >= o) ? tmp[t - o] : 0; __syncthreads();
        tmp[t] += u; __syncthreads();
    }
    if (t < SCAN_B) psum[t] = tmp[t] - v;   // exclusive
    if (t == 0) rowptr[NN] = NE;
}

__global__ __launch_bounds__(256) void k_scan3(const int* __restrict__ rp_local, const int* __restrict__ psum,
                                               int* __restrict__ rowptr, int* __restrict__ wptr) {
    int i = blockIdx.x * 256 + threadIdx.x;
    if (i < NN) {
        int v = rp_local[i] + psum[blockIdx.x];
        rowptr[i] = v;
        wptr[i] = v;
    }
}

// XCD-partitioned CSR fill (see k_deg comment).
__global__ __launch_bounds__(256) void k_fill(const int* __restrict__ src, const int* __restrict__ dst,
                                              int* __restrict__ wptr, int* __restrict__ csr_src) {
    const int grp = blockIdx.x & (NXCD - 1);
    const int slice = blockIdx.x >> 3;
    const int B = gridDim.x >> 3;
    const int lo = grp * RNG, hi = lo + RNG;
    for (int e = slice * 256 + threadIdx.x; e < NE; e += B * 256) {
        int d = dst[e];
        if (d >= lo && d < hi) {
            int pos = atomicAdd(wptr + d, 1);
            csr_src[pos] = src[e];
        }
    }
}

// ---------------- GEMM:  X(bf16) = (affine(H) @ W) * dinv[row] ----------------
template<int AFFINE>
__global__ __launch_bounds__(256) void k_gemm(
    const float* __restrict__ H, const float* __restrict__ W,
    const float* __restrict__ sc, const float* __restrict__ sh,
    const float* __restrict__ dinv, unsigned short* __restrict__ X)
{
    __shared__ float hs[64][132];
    __shared__ float ws[32][128];
    const int tid = threadIdx.x;
    const int base = blockIdx.x * 64;
    const int ct = tid & 15, rt = tid >> 4;
    const int r0 = rt * 4;
    const int cA = ct * 4, cB = cA + 64;

    #pragma unroll
    for (int i = 0; i < 8; ++i) {
        int idx4 = tid + i * 256;
        int r = idx4 >> 5;
        int c = (idx4 & 31) * 4;
        int row = base + r;
        float4 v = make_float4(0.f, 0.f, 0.f, 0.f);
        if (row < NN) v = *(const float4*)(H + (size_t)row * DH + c);
        if (AFFINE) {
            v.x = v.x * sc[c + 0] + sh[c + 0];
            v.y = v.y * sc[c + 1] + sh[c + 1];
            v.z = v.z * sc[c + 2] + sh[c + 2];
            v.w = v.w * sc[c + 3] + sh[c + 3];
        }
        *(float4*)&hs[r][c] = v;
    }

    float acc[4][8];
    #pragma unroll
    for (int i = 0; i < 4; ++i)
        #pragma unroll
        for (int j = 0; j < 8; ++j) acc[i][j] = 0.f;

    for (int kk = 0; kk < DH; kk += 32) {
        __syncthreads();
        #pragma unroll
        for (int i = 0; i < 4; ++i) {
            int idx4 = tid + i * 256;
            int k = idx4 >> 5;
            int c = (idx4 & 31) * 4;
            *(float4*)&ws[k][c] = *(const float4*)(W + (size_t)(kk + k) * DH + c);
        }
        __syncthreads();
        #pragma unroll
        for (int k = 0; k < 32; ++k) {
            float4 w0 = *(const float4*)&ws[k][cA];
            float4 w1 = *(const float4*)&ws[k][cB];
            #pragma unroll
            for (int i = 0; i < 4; ++i) {
                float h = hs[r0 + i][kk + k];
                acc[i][0] += h * w0.x; acc[i][1] += h * w0.y;
                acc[i][2] += h * w0.z; acc[i][3] += h * w0.w;
                acc[i][4] += h * w1.x; acc[i][5] += h * w1.y;
                acc[i][6] += h * w1.z; acc[i][7] += h * w1.w;
            }
        }
    }

    #pragma unroll
    for (int i = 0; i < 4; ++i) {
        int row = base + r0 + i;
        if (row < NN) {
            float di = dinv[row];
            ushort4 o0 = make_ushort4(f2bf(acc[i][0] * di), f2bf(acc[i][1] * di),
                                      f2bf(acc[i][2] * di), f2bf(acc[i][3] * di));
            ushort4 o1 = make_ushort4(f2bf(acc[i][4] * di), f2bf(acc[i][5] * di),
                                      f2bf(acc[i][6] * di), f2bf(acc[i][7] * di));
            *(ushort4*)(X + (size_t)row * DH + cA) = o0;
            *(ushort4*)(X + (size_t)row * DH + cB) = o1;
        }
    }
}

// -------- fused gather-aggregate + self-loop + bias + SELU --------
// X is bf16: row = 256B.  Half-wave (32 lanes x ushort4=8B) covers one row,
// so one 64-lane VMEM instr gathers TWO edges; 4 loads (8 edges) in flight.
__global__ __launch_bounds__(256) void k_agg(
    const unsigned short* __restrict__ X, const int* __restrict__ rowptr,
    const int* __restrict__ csr_src, const float* __restrict__ dinv,
    const float* __restrict__ bias, float* __restrict__ Y)
{
    int node = blockIdx.x * 4 + (threadIdx.x >> 6);
    if (node >= NN) return;
    const int lane = threadIdx.x & 63;
    const int half = lane >> 5;
    const int qc = lane & 31;
    const ushort4* __restrict__ X4 = (const ushort4*)X;   // row stride 32

    float4 accA = make_float4(0.f, 0.f, 0.f, 0.f);
    float4 accB = make_float4(0.f, 0.f, 0.f, 0.f);
    const int jb = rowptr[node], je = rowptr[node + 1];
    const int cnt = je - jb;

    for (int base = 0; base < cnt; base += 64) {
        int m = cnt - base; if (m > 64) m = 64;
        int idx_l = (base + lane < cnt) ? csr_src[jb + base + lane] : 0;
        int t = 0;
        for (; t + 8 <= m; t += 8) {
            int iA = __shfl(idx_l, t + half);
            int iB = __shfl(idx_l, t + 2 + half);
            int iC = __shfl(idx_l, t + 4 + half);
            int iD = __shfl(idx_l, t + 6 + half);
            ushort4 vA = X4[(size_t)iA * 32 + qc];
            ushort4 vB = X4[(size_t)iB * 32 + qc];
            ushort4 vC = X4[(size_t)iC * 32 + qc];
            ushort4 vD = X4[(size_t)iD * 32 + qc];
            accA.x += bf2f(vA.x); accA.y += bf2f(vA.y); accA.z += bf2f(vA.z); accA.w += bf2f(vA.w);
            accB.x += bf2f(vB.x); accB.y += bf2f(vB.y); accB.z += bf2f(vB.z); accB.w += bf2f(vB.w);
            accA.x += bf2f(vC.x); accA.y += bf2f(vC.y); accA.z += bf2f(vC.z); accA.w += bf2f(vC.w);
            accB.x += bf2f(vD.x); accB.y += bf2f(vD.y); accB.z += bf2f(vD.z); accB.w += bf2f(vD.w);
        }
        for (; t < m; t += 4) {
            int eA = t + half;
            int eB = t + 2 + half;
            int iA = __shfl(idx_l, eA);
            int iB = __shfl(idx_l, eB);
            float wA = (eA < m) ? 1.f : 0.f;
            float wB = (eB < m) ? 1.f : 0.f;
            ushort4 vA = X4[(size_t)iA * 32 + qc];
            ushort4 vB = X4[(size_t)iB * 32 + qc];
            accA.x += wA * bf2f(vA.x); accA.y += wA * bf2f(vA.y);
            accA.z += wA * bf2f(vA.z); accA.w += wA * bf2f(vA.w);
            accB.x += wB * bf2f(vB.x); accB.y += wB * bf2f(vB.y);
            accB.z += wB * bf2f(vB.z); accB.w += wB * bf2f(vB.w);
        }
    }

    float4 acc;
    acc.x = accA.x + accB.x; acc.y = accA.y + accB.y;
    acc.z = accA.z + accB.z; acc.w = accA.w + accB.w;

    acc.x += __shfl_xor(acc.x, 32);
    acc.y += __shfl_xor(acc.y, 32);
    acc.z += __shfl_xor(acc.z, 32);
    acc.w += __shfl_xor(acc.w, 32);

    if (half == 0) {
        ushort4 sv = X4[(size_t)node * 32 + qc];
        float di = dinv[node];
        float4 bv = ((const float4*)bias)[qc];
        float4 o;
        o.x = selu_f(di * (acc.x + bf2f(sv.x)) + bv.x);
        o.y = selu_f(di * (acc.y + bf2f(sv.y)) + bv.y);
        o.z = selu_f(di * (acc.z + bf2f(sv.z)) + bv.z);
        o.w = selu_f(di * (acc.w + bf2f(sv.w)) + bv.w);
        ((float4*)Y)[(size_t)node * 32 + qc] = o;
    }
}

// ---------------- BN stats over Y (f32) ----------------
__global__ __launch_bounds__(256) void k_stats(const float* __restrict__ Y,
                                               float* __restrict__ ssum, float* __restrict__ ssq)
{
    const int tid = threadIdx.x;
    float s = 0.f, s2 = 0.f;
    const int total = NN * DH;
    const int stride = gridDim.x * 256;
    for (int idx = blockIdx.x * 256 + tid; idx < total; idx += stride) {
        float y = Y[idx];
        s += y; s2 += y * y;
    }
    __shared__ float r1[256], r2[256];
    r1[tid] = s; r2[tid] = s2;
    __syncthreads();
    if (tid < 128) {
        unsafeAtomicAdd(ssum + tid, r1[tid] + r1[tid + 128]);
        unsafeAtomicAdd(ssq + tid, r2[tid] + r2[tid + 128]);
    }
}

__global__ void k_bnfin(const float* __restrict__ ssum, const float* __restrict__ ssq,
                        const float* __restrict__ gamma, const float* __restrict__ beta,
                        float* __restrict__ sc, float* __restrict__ sh)
{
    int c = threadIdx.x;
    float mean = ssum[c] * (1.f / NN);
    float var = ssq[c] * (1.f / NN) - mean * mean;
    float s = gamma[c] * rsqrtf(var + 1e-5f);
    sc[c] = s;
    sh[c] = beta[c] - mean * s;
}

// ---------------- pooling: batch is sorted -> per-graph segment sum ----------------
__global__ __launch_bounds__(128) void k_pool(const float* __restrict__ Y,
                                              const int* __restrict__ batch, float* __restrict__ hg)
{
    int g = blockIdx.x;
    __shared__ int bounds[2];
    if (threadIdx.x < 2) {
        int target = g + threadIdx.x;
        int lo = 0, hi = NN;
        while (lo < hi) { int mid = (lo + hi) >> 1; if (batch[mid] < target) lo = mid + 1; else hi = mid; }
        bounds[threadIdx.x] = lo;
    }
    __syncthreads();
    int s = bounds[0], e = bounds[1];
    int c = threadIdx.x;
    float acc = 0.f;
    for (int i = s; i < e; ++i) acc += Y[(size_t)i * DH + c];
    hg[(size_t)g * DH + c] = acc;
}

// ---------------- final MLP ----------------
__global__ __launch_bounds__(128) void k_mlp(
    const float* __restrict__ hg, const float* __restrict__ mol,
    const float* __restrict__ Wf1, const float* __restrict__ bf1,
    const float* __restrict__ Wf2, const float* __restrict__ bf2,
    float* __restrict__ out)
{
    int g = blockIdx.x, c = threadIdx.x;
    __shared__ float in_s[192];
    in_s[c] = hg[(size_t)g * DH + c];
    if (c < 64) in_s[128 + c] = mol[(size_t)g * 64 + c];
    __syncthreads();
    float acc = bf1[c];
    #pragma unroll 8
    for (int k = 0; k < 192; ++k) acc += in_s[k] * Wf1[k * DH + c];
    float h = selu_f(acc);
    float pv = h * Wf2[c];
    #pragma unroll
    for (int o = 32; o > 0; o >>= 1) pv += __shfl_down(pv, o);
    __shared__ float wsum[2];
    if ((c & 63) == 0) wsum[c >> 6] = pv;
    __syncthreads();
    if (c == 0) out[g] = wsum[0] + wsum[1] + bf2[0];
}

extern "C" void kernel_launch(void* const* d_in, const int* in_sizes, int n_in,
                              void* d_out, int out_size, void* d_ws, size_t ws_size,
                              hipStream_t stream)
{
    const float* x   = (const float*)d_in[0];
    const int* ei    = (const int*)d_in[1];
    const int* batch = (const int*)d_in[2];
    const float* mol = (const float*)d_in[3];
    const float* W1  = (const float*)d_in[4];  const float* b1  = (const float*)d_in[5];
    const float* g1  = (const float*)d_in[6];  const float* be1 = (const float*)d_in[7];
    const float* W2  = (const float*)d_in[8];  const float* b2  = (const float*)d_in[9];
    const float* g2  = (const float*)d_in[10]; const float* be2 = (const float*)d_in[11];
    const float* W3  = (const float*)d_in[12]; const float* b3  = (const float*)d_in[13];
    const float* Wf1 = (const float*)d_in[14]; const float* bf1 = (const float*)d_in[15];
    const float* Wf2 = (const float*)d_in[16]; const float* bf2 = (const float*)d_in[17];
    const int* srcv = ei;
    const int* dstv = ei + NE;
    float* out = (float*)d_out;

    char* p = (char*)d_ws;
    size_t off = 0;
    auto alloc = [&](size_t bytes) { void* q = p + off; off += (bytes + 255) & ~(size_t)255; return q; };
    float*          bufY  = (float*)alloc((size_t)NN * DH * 4);          // f32 activations
    unsigned short* bufX  = (unsigned short*)alloc((size_t)NN * DH * 2); // bf16 gather buffer
    int*   deg    = (int*)alloc((size_t)NN * 4);
    float* dinv   = (float*)alloc((size_t)NN * 4);
    int*   rowptr = (int*)alloc((size_t)(NN + 1) * 4);
    int*   wptr   = (int*)alloc((size_t)NN * 4);
    int*   rp_loc = (int*)alloc((size_t)NN * 4);
    int*   psum   = (int*)alloc((size_t)512 * 4);
    int*   csr    = (int*)alloc((size_t)NE * 4);
    float* ssum   = (float*)alloc(512);
    float* ssq    = (float*)alloc(512);
    float* scb    = (float*)alloc(512);
    float* shb    = (float*)alloc(512);
    float* hg     = (float*)alloc((size_t)NG * DH * 4);

    const int NB = (NN + 255) / 256;   // = SCAN_B
    const int XB = 2048;               // 256 blocks per XCD-group
    const int GB = (NN + 63) / 64;
    const int AB = (NN + 3) / 4;

    // ---- CSR build (amortized over 3 aggregations) ----
    hipMemsetAsync(deg, 0, (size_t)NN * 4, stream);
    k_deg<<<XB, 256, 0, stream>>>(dstv, deg);
    k_dinv<<<NB, 256, 0, stream>>>(deg, dinv);
    k_scan1<<<NB, 256, 0, stream>>>(deg, rp_loc, psum);
    k_scan2<<<1, 512, 0, stream>>>(psum, rowptr);
    k_scan3<<<NB, 256, 0, stream>>>(rp_loc, psum, rowptr, wptr);
    k_fill<<<XB, 256, 0, stream>>>(srcv, dstv, wptr, csr);

    // ---- Layer 1 ----
    k_gemm<0><<<GB, 256, 0, stream>>>(x, W1, nullptr, nullptr, dinv, bufX);
    k_agg<<<AB, 256, 0, stream>>>(bufX, rowptr, csr, dinv, b1, bufY);
    hipMemsetAsync(ssum, 0, 512, stream);
    hipMemsetAsync(ssq, 0, 512, stream);
    k_stats<<<512, 256, 0, stream>>>(bufY, ssum, ssq);
    k_bnfin<<<1, 128, 0, stream>>>(ssum, ssq, g1, be1, scb, shb);

    // ---- Layer 2 ----
    k_gemm<1><<<GB, 256, 0, stream>>>(bufY, W2, scb, shb, dinv, bufX);
    k_agg<<<AB, 256, 0, stream>>>(bufX, rowptr, csr, dinv, b2, bufY);
    hipMemsetAsync(ssum, 0, 512, stream);
    hipMemsetAsync(ssq, 0, 512, stream);
    k_stats<<<512, 256, 0, stream>>>(bufY, ssum, ssq);
    k_bnfin<<<1, 128, 0, stream>>>(ssum, ssq, g2, be2, scb, shb);

    // ---- Layer 3 ----
    k_gemm<1><<<GB, 256, 0, stream>>>(bufY, W3, scb, shb, dinv, bufX);
    k_agg<<<AB, 256, 0, stream>>>(bufX, rowptr, csr, dinv, b3, bufY);
    k_pool<<<NG, 128, 0, stream>>>(bufY, batch, hg);

    k_mlp<<<NG, 128, 0, stream>>>(hg, mol, Wf1, bf1, Wf2, bf2, out);
}

// Round 15
// 644.115 us; speedup vs baseline: 1.5031x; 1.1831x over previous
//
#include <hip/hip_runtime.h>

#define NN 100000      // nodes
#define NE 1600000     // edges
#define NG 2048        // graphs
#define DH 128         // feature dim
#define SCAN_B 391     // ceil(NN/256)
#define NXCD 8
#define RNG 12500      // NN / NXCD

typedef __attribute__((ext_vector_type(8))) short bh8;   // 8 bf16 (4 VGPRs)
typedef __attribute__((ext_vector_type(4))) float fx4;   // MFMA accumulator

__device__ __forceinline__ float selu_f(float x) {
    return x > 0.f ? 1.0507009873554805f * x : 1.7580993408473766f * expm1f(x);
}

// f32 -> bf16 round-to-nearest-even (bit trick), and back
__device__ __forceinline__ unsigned short f2bf(float f) {
    unsigned int u = __float_as_uint(f);
    return (unsigned short)((u + 0x7FFFu + ((u >> 16) & 1u)) >> 16);
}
__device__ __forceinline__ float bf2f(unsigned short s) {
    return __uint_as_float(((unsigned int)s) << 16);
}

// ---------------- CSR build (XCD-partitioned scatter; see r11/r12) ----------------
__global__ __launch_bounds__(256) void k_deg(const int* __restrict__ dst, int* __restrict__ deg) {
    const int grp = blockIdx.x & (NXCD - 1);
    const int slice = blockIdx.x >> 3;
    const int B = gridDim.x >> 3;
    const int lo = grp * RNG, hi = lo + RNG;
    for (int e = slice * 256 + threadIdx.x; e < NE; e += B * 256) {
        int d = dst[e];
        if (d >= lo && d < hi) atomicAdd(deg + d, 1);
    }
}

__global__ __launch_bounds__(256) void k_dinv(const int* __restrict__ deg, float* __restrict__ dinv) {
    int i = blockIdx.x * 256 + threadIdx.x;
    if (i < NN) dinv[i] = rsqrtf((float)deg[i] + 1.0f);
}

__global__ __launch_bounds__(256) void k_scan1(const int* __restrict__ deg,
                                               int* __restrict__ rp_local, int* __restrict__ psum) {
    __shared__ int tmp[256];
    int t = threadIdx.x;
    int i = blockIdx.x * 256 + t;
    int v = (i < NN) ? deg[i] : 0;
    tmp[t] = v; __syncthreads();
    #pragma unroll
    for (int o = 1; o < 256; o <<= 1) {
        int u = (t >= o) ? tmp[t - o] : 0; __syncthreads();
        tmp[t] += u; __syncthreads();
    }
    if (i < NN) rp_local[i] = tmp[t] - v;
    if (t == 255) psum[blockIdx.x] = tmp[t];
}

__global__ __launch_bounds__(512) void k_scan2(int* __restrict__ psum, int* __restrict__ rowptr) {
    __shared__ int tmp[512];
    int t = threadIdx.x;
    int v = (t < SCAN_B) ? psum[t] : 0;
    tmp[t] = v; __syncthreads();
    #pragma unroll
    for (int o = 1; o < 512; o <<= 1) {
        int u = (t >= o) ? tmp[t - o] : 0; __syncthreads();
        tmp[t] += u; __syncthreads();
    }
    if (t < SCAN_B) psum[t] = tmp[t] - v;   // exclusive
    if (t == 0) rowptr[NN] = NE;
}

__global__ __launch_bounds__(256) void k_scan3(const int* __restrict__ rp_local, const int* __restrict__ psum,
                                               int* __restrict__ rowptr, int* __restrict__ wptr) {
    int i = blockIdx.x * 256 + threadIdx.x;
    if (i < NN) {
        int v = rp_local[i] + psum[blockIdx.x];
        rowptr[i] = v;
        wptr[i] = v;
    }
}

__global__ __launch_bounds__(256) void k_fill(const int* __restrict__ src, const int* __restrict__ dst,
                                              int* __restrict__ wptr, int* __restrict__ csr_src) {
    const int grp = blockIdx.x & (NXCD - 1);
    const int slice = blockIdx.x >> 3;
    const int B = gridDim.x >> 3;
    const int lo = grp * RNG, hi = lo + RNG;
    for (int e = slice * 256 + threadIdx.x; e < NE; e += B * 256) {
        int d = dst[e];
        if (d >= lo && d < hi) {
            int pos = atomicAdd(wptr + d, 1);
            csr_src[pos] = src[e];
        }
    }
}

// ---------------- W pack: f32 [128][128] -> bf16 B-fragments ----------------
// P[kt*4096 + nt*512 + lane*8 + j] = bf16(W[kt*32 + (lane>>4)*8 + j][nt*16 + (lane&15)])
__global__ __launch_bounds__(256) void k_wpack(const float* __restrict__ W, unsigned short* __restrict__ P) {
    int idx = blockIdx.x * 256 + threadIdx.x;
    if (idx >= 128 * 128) return;
    int j  = idx & 7;
    int l  = (idx >> 3) & 63;
    int nt = (idx >> 9) & 7;
    int kt = idx >> 12;
    int k = kt * 32 + (l >> 4) * 8 + j;
    int n = nt * 16 + (l & 15);
    P[idx] = f2bf(W[k * 128 + n]);
}

// ---------------- MFMA GEMM:  X(bf16) = (affine(H) @ W) * dinv[row] ----------------
// 64 rows/block, 4 waves, wave w owns rows w*16..w*16+15.
// A staged f32->bf16 in LDS (affine fused); B-frags read pre-packed from L2.
template<int AFFINE>
__global__ __launch_bounds__(256) void k_gemm(
    const float* __restrict__ H, const unsigned short* __restrict__ P,
    const float* __restrict__ sc, const float* __restrict__ sh,
    const float* __restrict__ dinv, unsigned short* __restrict__ X)
{
    __shared__ unsigned short As[64][136];   // +8 bf16 pad -> 2-way-free bank pattern
    const int tid = threadIdx.x;
    const int base = blockIdx.x * 64;

    #pragma unroll
    for (int i = 0; i < 4; ++i) {
        int idx8 = tid + i * 256;        // over 64 rows x 16 col-groups of 8
        int r = idx8 >> 4;
        int c = (idx8 & 15) * 8;
        int row = base + r;
        float4 v0 = make_float4(0.f, 0.f, 0.f, 0.f);
        float4 v1 = make_float4(0.f, 0.f, 0.f, 0.f);
        if (row < NN) {
            v0 = *(const float4*)(H + (size_t)row * DH + c);
            v1 = *(const float4*)(H + (size_t)row * DH + c + 4);
        }
        if (AFFINE) {
            v0.x = v0.x * sc[c + 0] + sh[c + 0];
            v0.y = v0.y * sc[c + 1] + sh[c + 1];
            v0.z = v0.z * sc[c + 2] + sh[c + 2];
            v0.w = v0.w * sc[c + 3] + sh[c + 3];
            v1.x = v1.x * sc[c + 4] + sh[c + 4];
            v1.y = v1.y * sc[c + 5] + sh[c + 5];
            v1.z = v1.z * sc[c + 6] + sh[c + 6];
            v1.w = v1.w * sc[c + 7] + sh[c + 7];
        }
        ushort4 u0 = make_ushort4(f2bf(v0.x), f2bf(v0.y), f2bf(v0.z), f2bf(v0.w));
        ushort4 u1 = make_ushort4(f2bf(v1.x), f2bf(v1.y), f2bf(v1.z), f2bf(v1.w));
        *(ushort4*)&As[r][c] = u0;
        *(ushort4*)&As[r][c + 4] = u1;
    }
    __syncthreads();

    const int wv = tid >> 6;
    const int lane = tid & 63;
    const int arow = lane & 15;
    const int kg = lane >> 4;

    fx4 acc[8];
    #pragma unroll
    for (int nt = 0; nt < 8; ++nt) acc[nt] = (fx4){0.f, 0.f, 0.f, 0.f};

    #pragma unroll
    for (int kt = 0; kt < 4; ++kt) {
        bh8 a = *(const bh8*)&As[wv * 16 + arow][kt * 32 + kg * 8];
        #pragma unroll
        for (int nt = 0; nt < 8; ++nt) {
            bh8 b = *(const bh8*)(P + kt * 4096 + nt * 512 + lane * 8);
            acc[nt] = __builtin_amdgcn_mfma_f32_16x16x32_bf16(a, b, acc[nt], 0, 0, 0);
        }
    }

    // C/D: row = (lane>>4)*4 + j, col = nt*16 + (lane&15)   [verified mapping]
    #pragma unroll
    for (int j = 0; j < 4; ++j) {
        int row = base + wv * 16 + (lane >> 4) * 4 + j;
        if (row < NN) {
            float di = dinv[row];
            #pragma unroll
            for (int nt = 0; nt < 8; ++nt) {
                X[(size_t)row * DH + nt * 16 + (lane & 15)] = f2bf(acc[nt][j] * di);
            }
        }
    }
}

// -------- fused gather-aggregate + self-loop + bias + SELU (bf16 X) --------
__global__ __launch_bounds__(256) void k_agg(
    const unsigned short* __restrict__ X, const int* __restrict__ rowptr,
    const int* __restrict__ csr_src, const float* __restrict__ dinv,
    const float* __restrict__ bias, float* __restrict__ Y)
{
    int node = blockIdx.x * 4 + (threadIdx.x >> 6);
    if (node >= NN) return;
    const int lane = threadIdx.x & 63;
    const int half = lane >> 5;
    const int qc = lane & 31;
    const ushort4* __restrict__ X4 = (const ushort4*)X;   // row stride 32

    float4 accA = make_float4(0.f, 0.f, 0.f, 0.f);
    float4 accB = make_float4(0.f, 0.f, 0.f, 0.f);
    const int jb = rowptr[node], je = rowptr[node + 1];
    const int cnt = je - jb;

    for (int base = 0; base < cnt; base += 64) {
        int m = cnt - base; if (m > 64) m = 64;
        int idx_l = (base + lane < cnt) ? csr_src[jb + base + lane] : 0;
        int t = 0;
        for (; t + 8 <= m; t += 8) {
            int iA = __shfl(idx_l, t + half);
            int iB = __shfl(idx_l, t + 2 + half);
            int iC = __shfl(idx_l, t + 4 + half);
            int iD = __shfl(idx_l, t + 6 + half);
            ushort4 vA = X4[(size_t)iA * 32 + qc];
            ushort4 vB = X4[(size_t)iB * 32 + qc];
            ushort4 vC = X4[(size_t)iC * 32 + qc];
            ushort4 vD = X4[(size_t)iD * 32 + qc];
            accA.x += bf2f(vA.x); accA.y += bf2f(vA.y); accA.z += bf2f(vA.z); accA.w += bf2f(vA.w);
            accB.x += bf2f(vB.x); accB.y += bf2f(vB.y); accB.z += bf2f(vB.z); accB.w += bf2f(vB.w);
            accA.x += bf2f(vC.x); accA.y += bf2f(vC.y); accA.z += bf2f(vC.z); accA.w += bf2f(vC.w);
            accB.x += bf2f(vD.x); accB.y += bf2f(vD.y); accB.z += bf2f(vD.z); accB.w += bf2f(vD.w);
        }
        for (; t < m; t += 4) {
            int eA = t + half;
            int eB = t + 2 + half;
            int iA = __shfl(idx_l, eA);
            int iB = __shfl(idx_l, eB);
            float wA = (eA < m) ? 1.f : 0.f;
            float wB = (eB < m) ? 1.f : 0.f;
            ushort4 vA = X4[(size_t)iA * 32 + qc];
            ushort4 vB = X4[(size_t)iB * 32 + qc];
            accA.x += wA * bf2f(vA.x); accA.y += wA * bf2f(vA.y);
            accA.z += wA * bf2f(vA.z); accA.w += wA * bf2f(vA.w);
            accB.x += wB * bf2f(vB.x); accB.y += wB * bf2f(vB.y);
            accB.z += wB * bf2f(vB.z); accB.w += wB * bf2f(vB.w);
        }
    }

    float4 acc;
    acc.x = accA.x + accB.x; acc.y = accA.y + accB.y;
    acc.z = accA.z + accB.z; acc.w = accA.w + accB.w;

    acc.x += __shfl_xor(acc.x, 32);
    acc.y += __shfl_xor(acc.y, 32);
    acc.z += __shfl_xor(acc.z, 32);
    acc.w += __shfl_xor(acc.w, 32);

    if (half == 0) {
        ushort4 sv = X4[(size_t)node * 32 + qc];
        float di = dinv[node];
        float4 bv = ((const float4*)bias)[qc];
        float4 o;
        o.x = selu_f(di * (acc.x + bf2f(sv.x)) + bv.x);
        o.y = selu_f(di * (acc.y + bf2f(sv.y)) + bv.y);
        o.z = selu_f(di * (acc.z + bf2f(sv.z)) + bv.z);
        o.w = selu_f(di * (acc.w + bf2f(sv.w)) + bv.w);
        ((float4*)Y)[(size_t)node * 32 + qc] = o;
    }
}

// ---------------- BN stats over Y (f32) ----------------
__global__ __launch_bounds__(256) void k_stats(const float* __restrict__ Y,
                                               float* __restrict__ ssum, float* __restrict__ ssq)
{
    const int tid = threadIdx.x;
    float s = 0.f, s2 = 0.f;
    const int total = NN * DH;
    const int stride = gridDim.x * 256;
    for (int idx = blockIdx.x * 256 + tid; idx < total; idx += stride) {
        float y = Y[idx];
        s += y; s2 += y * y;
    }
    __shared__ float r1[256], r2[256];
    r1[tid] = s; r2[tid] = s2;
    __syncthreads();
    if (tid < 128) {
        unsafeAtomicAdd(ssum + tid, r1[tid] + r1[tid + 128]);
        unsafeAtomicAdd(ssq + tid, r2[tid] + r2[tid + 128]);
    }
}

__global__ void k_bnfin(const float* __restrict__ ssum, const float* __restrict__ ssq,
                        const float* __restrict__ gamma, const float* __restrict__ beta,
                        float* __restrict__ sc, float* __restrict__ sh)
{
    int c = threadIdx.x;
    float mean = ssum[c] * (1.f / NN);
    float var = ssq[c] * (1.f / NN) - mean * mean;
    float s = gamma[c] * rsqrtf(var + 1e-5f);
    sc[c] = s;
    sh[c] = beta[c] - mean * s;
}

// ---------------- pooling ----------------
__global__ __launch_bounds__(128) void k_pool(const float* __restrict__ Y,
                                              const int* __restrict__ batch, float* __restrict__ hg)
{
    int g = blockIdx.x;
    __shared__ int bounds[2];
    if (threadIdx.x < 2) {
        int target = g + threadIdx.x;
        int lo = 0, hi = NN;
        while (lo < hi) { int mid = (lo + hi) >> 1; if (batch[mid] < target) lo = mid + 1; else hi = mid; }
        bounds[threadIdx.x] = lo;
    }
    __syncthreads();
    int s = bounds[0], e = bounds[1];
    int c = threadIdx.x;
    float acc = 0.f;
    for (int i = s; i < e; ++i) acc += Y[(size_t)i * DH + c];
    hg[(size_t)g * DH + c] = acc;
}

// ---------------- final MLP ----------------
__global__ __launch_bounds__(128) void k_mlp(
    const float* __restrict__ hg, const float* __restrict__ mol,
    const float* __restrict__ Wf1, const float* __restrict__ bf1,
    const float* __restrict__ Wf2, const float* __restrict__ bf2,
    float* __restrict__ out)
{
    int g = blockIdx.x, c = threadIdx.x;
    __shared__ float in_s[192];
    in_s[c] = hg[(size_t)g * DH + c];
    if (c < 64) in_s[128 + c] = mol[(size_t)g * 64 + c];
    __syncthreads();
    float acc = bf1[c];
    #pragma unroll 8
    for (int k = 0; k < 192; ++k) acc += in_s[k] * Wf1[k * DH + c];
    float h = selu_f(acc);
    float pv = h * Wf2[c];
    #pragma unroll
    for (int o = 32; o > 0; o >>= 1) pv += __shfl_down(pv, o);
    __shared__ float wsum[2];
    if ((c & 63) == 0) wsum[c >> 6] = pv;
    __syncthreads();
    if (c == 0) out[g] = wsum[0] + wsum[1] + bf2[0];
}

extern "C" void kernel_launch(void* const* d_in, const int* in_sizes, int n_in,
                              void* d_out, int out_size, void* d_ws, size_t ws_size,
                              hipStream_t stream)
{
    const float* x   = (const float*)d_in[0];
    const int* ei    = (const int*)d_in[1];
    const int* batch = (const int*)d_in[2];
    const float* mol = (const float*)d_in[3];
    const float* W1  = (const float*)d_in[4];  const float* b1  = (const float*)d_in[5];
    const float* g1  = (const float*)d_in[6];  const float* be1 = (const float*)d_in[7];
    const float* W2  = (const float*)d_in[8];  const float* b2  = (const float*)d_in[9];
    const float* g2  = (const float*)d_in[10]; const float* be2 = (const float*)d_in[11];
    const float* W3  = (const float*)d_in[12]; const float* b3  = (const float*)d_in[13];
    const float* Wf1 = (const float*)d_in[14]; const float* bf1 = (const float*)d_in[15];
    const float* Wf2 = (const float*)d_in[16]; const float* bf2 = (const float*)d_in[17];
    const int* srcv = ei;
    const int* dstv = ei + NE;
    float* out = (float*)d_out;

    char* p = (char*)d_ws;
    size_t off = 0;
    auto alloc = [&](size_t bytes) { void* q = p + off; off += (bytes + 255) & ~(size_t)255; return q; };
    float*          bufY  = (float*)alloc((size_t)NN * DH * 4);          // f32 activations
    unsigned short* bufX  = (unsigned short*)alloc((size_t)NN * DH * 2); // bf16 gather buffer
    int*   deg    = (int*)alloc((size_t)NN * 4);
    float* dinv   = (float*)alloc((size_t)NN * 4);
    int*   rowptr = (int*)alloc((size_t)(NN + 1) * 4);
    int*   wptr   = (int*)alloc((size_t)NN * 4);
    int*   rp_loc = (int*)alloc((size_t)NN * 4);
    int*   psum   = (int*)alloc((size_t)512 * 4);
    int*   csr    = (int*)alloc((size_t)NE * 4);
    float* ssum   = (float*)alloc(512);
    float* ssq    = (float*)alloc(512);
    float* scb    = (float*)alloc(512);
    float* shb    = (float*)alloc(512);
    float* hg     = (float*)alloc((size_t)NG * DH * 4);
    unsigned short* wp1 = (unsigned short*)alloc((size_t)128 * 128 * 2);
    unsigned short* wp2 = (unsigned short*)alloc((size_t)128 * 128 * 2);
    unsigned short* wp3 = (unsigned short*)alloc((size_t)128 * 128 * 2);

    const int NB = (NN + 255) / 256;   // = SCAN_B
    const int XB = 2048;               // 256 blocks per XCD-group
    const int GB = (NN + 63) / 64;
    const int AB = (NN + 3) / 4;
    const int WB = (128 * 128 + 255) / 256;

    // ---- W packs + CSR build ----
    k_wpack<<<WB, 256, 0, stream>>>(W1, wp1);
    k_wpack<<<WB, 256, 0, stream>>>(W2, wp2);
    k_wpack<<<WB, 256, 0, stream>>>(W3, wp3);
    hipMemsetAsync(deg, 0, (size_t)NN * 4, stream);
    k_deg<<<XB, 256, 0, stream>>>(dstv, deg);
    k_dinv<<<NB, 256, 0, stream>>>(deg, dinv);
    k_scan1<<<NB, 256, 0, stream>>>(deg, rp_loc, psum);
    k_scan2<<<1, 512, 0, stream>>>(psum, rowptr);
    k_scan3<<<NB, 256, 0, stream>>>(rp_loc, psum, rowptr, wptr);
    k_fill<<<XB, 256, 0, stream>>>(srcv, dstv, wptr, csr);

    // ---- Layer 1 ----
    k_gemm<0><<<GB, 256, 0, stream>>>(x, wp1, nullptr, nullptr, dinv, bufX);
    k_agg<<<AB, 256, 0, stream>>>(bufX, rowptr, csr, dinv, b1, bufY);
    hipMemsetAsync(ssum, 0, 512, stream);
    hipMemsetAsync(ssq, 0, 512, stream);
    k_stats<<<512, 256, 0, stream>>>(bufY, ssum, ssq);
    k_bnfin<<<1, 128, 0, stream>>>(ssum, ssq, g1, be1, scb, shb);

    // ---- Layer 2 ----
    k_gemm<1><<<GB, 256, 0, stream>>>(bufY, wp2, scb, shb, dinv, bufX);
    k_agg<<<AB, 256, 0, stream>>>(bufX, rowptr, csr, dinv, b2, bufY);
    hipMemsetAsync(ssum, 0, 512, stream);
    hipMemsetAsync(ssq, 0, 512, stream);
    k_stats<<<512, 256, 0, stream>>>(bufY, ssum, ssq);
    k_bnfin<<<1, 128, 0, stream>>>(ssum, ssq, g2, be2, scb, shb);

    // ---- Layer 3 ----
    k_gemm<1><<<GB, 256, 0, stream>>>(bufY, wp3, scb, shb, dinv, bufX);
    k_agg<<<AB, 256, 0, stream>>>(bufX, rowptr, csr, dinv, b3, bufY);
    k_pool<<<NG, 128, 0, stream>>>(bufY, batch, hg);

    k_mlp<<<NG, 128, 0, stream>>>(hg, mol, Wf1, bf1, Wf2, bf2, out);
}